// Round 12
// baseline (167.533 us; speedup 1.0000x reference)
//
#include <hip/hip_runtime.h>

#define BB 16
#define CC 80
#define DD 1024
#define HW 196
#define NSP (BB * HW)        // 3136 = 49 full waves, zero lane waste
#define NCH 8                // d-chunks of 128
#define DCH 128
#define CPB 4                // classes per scores block
#define NCQ (CC / CPB)       // 20 class-groups -> 2080 blocks (proven residency)
#define PG 16                // classes per pool block (4 per wave)
#define TWO_LOG2E 2.8853900817779268f

// ---------------- K1: scores + imgT side-product, FENCED PREFETCH ----------
// R5-proven structure (NCH=8, CPB=4, 2080 blocks) + explicit double-buffered
// quarter prefetch. sched_barrier(0) after each load batch forbids the
// compiler from sinking the prefetch into the compute region (R3's attempt
// was defeated exactly that way: VGPR fell to 44). Target: recover the
// ~25-30 us of quarter-boundary load stall that pins scores at 68 us.
// Stores x = -2*log2e * sum_d fa[d]/(e^{2 img w}+1); affine remainder
// cancels in softmax; exp2(x) == softmax numerator pre-max.
__global__ __launch_bounds__(256) void scores_k(const float* __restrict__ img,
                                                const float* __restrict__ word,
                                                const float* __restrict__ fa,
                                                float* __restrict__ partial,
                                                float* __restrict__ imgT) {
    const int g = blockIdx.x * 256 + threadIdx.x;
    if (g >= NSP) return;                           // wave-uniform exit
    const int b  = g / HW;
    const int hw = g - b * HW;
    const int d0 = blockIdx.y * DCH;
    const int c0 = blockIdx.z * CPB;
    const bool zz = (blockIdx.z == 0);

    const float* ip = img + ((size_t)b * DD + d0) * HW + hw;

    float p[CPB];
#pragma unroll
    for (int k = 0; k < CPB; ++k) p[k] = 0.f;

    float ivA[32], ivB[32];

    auto loadq = [&](float* iv, int q) {
        const float* qp = ip + (size_t)q * 32 * HW;
#pragma unroll
        for (int i = 0; i < 32; ++i)
            iv[i] = qp[(size_t)i * HW];
    };
    auto computeq = [&](float* iv, int q) {
        if (zz) {                                    // block-uniform branch
            float4* tp = (float4*)(imgT + (size_t)g * DD + d0 + q * 32);
#pragma unroll
            for (int i = 0; i < 8; ++i)
                tp[i] = make_float4(iv[4 * i], iv[4 * i + 1], iv[4 * i + 2], iv[4 * i + 3]);
        }
#pragma unroll
        for (int i = 0; i < 32; ++i)
            iv[i] *= TWO_LOG2E;                      // exp2(iv*w) == e^{2x}

        const float* fp = fa + d0 + q * 32;          // uniform -> SGPRs
#pragma unroll
        for (int k = 0; k < CPB; ++k) {
            const float* wp = word + (size_t)(c0 + k) * DD + d0 + q * 32;
            float p0 = 0.f, p1 = 0.f;
#pragma unroll
            for (int i = 0; i < 32; i += 2) {
                float y0 = iv[i]     * wp[i];
                float y1 = iv[i + 1] * wp[i + 1];
                float e0 = __builtin_amdgcn_exp2f(y0);
                float e1 = __builtin_amdgcn_exp2f(y1);
                float r0 = __builtin_amdgcn_rcpf(e0 + 1.f);
                float r1 = __builtin_amdgcn_rcpf(e1 + 1.f);
                p0 = fmaf(fp[i],     r0, p0);
                p1 = fmaf(fp[i + 1], r1, p1);
            }
            p[k] += p0 + p1;
        }
    };

    loadq(ivA, 0);
    __builtin_amdgcn_sched_barrier(0);   // loads of q0 issued before anything below
    loadq(ivB, 1);
    __builtin_amdgcn_sched_barrier(0);   // q1 prefetch in flight during q0 compute
    computeq(ivA, 0);
    loadq(ivA, 2);
    __builtin_amdgcn_sched_barrier(0);   // q2 prefetch in flight during q1 compute
    computeq(ivB, 1);
    loadq(ivB, 3);
    __builtin_amdgcn_sched_barrier(0);   // q3 prefetch in flight during q2 compute
    computeq(ivA, 2);
    computeq(ivB, 3);

#pragma unroll
    for (int k = 0; k < CPB; ++k)
        partial[(((size_t)b * NCH + blockIdx.y) * CC + (c0 + k)) * HW + hw]
            = (-TWO_LOG2E) * p[k];
}

// ---------------- K2: standalone softmax (proven R9/R10 shape) -------------
// Block per (b,c). Sums the 8 d-chunk partials, softmax via exp2. coef is
// aliased onto partial's ch=0 slice (unique reader of partial[b][*][c][*];
// reads complete before the write -- the LDS-reduction __syncthreads orders).
__global__ __launch_bounds__(256) void softmax_k(float* __restrict__ partial) {
    const int bc = blockIdx.x;
    const int b = bc / CC, c = bc - b * CC;
    const int t = threadIdx.x;

    float x = -3.4e38f;
    if (t < HW) {
        float P = 0.f;
#pragma unroll
        for (int ch = 0; ch < NCH; ++ch)
            P += partial[(((size_t)b * NCH + ch) * CC + c) * HW + t];
        x = P;                                       // already -2*log2e scaled
    }

    __shared__ float rmax[4], rsum[4];
    const int wv = t >> 6;

    float m = x;
#pragma unroll
    for (int off = 32; off >= 1; off >>= 1) m = fmaxf(m, __shfl_xor(m, off, 64));
    if ((t & 63) == 0) rmax[wv] = m;
    __syncthreads();
    m = fmaxf(fmaxf(rmax[0], rmax[1]), fmaxf(rmax[2], rmax[3]));

    float e = (t < HW) ? __builtin_amdgcn_exp2f(x - m) : 0.f;
    float s = e;
#pragma unroll
    for (int off = 32; off >= 1; off >>= 1) s += __shfl_xor(s, off, 64);
    if ((t & 63) == 0) rsum[wv] = s;
    __syncthreads();
    s = rsum[0] + rsum[1] + rsum[2] + rsum[3];

    if (t < HW)   // coef[b][c][t] aliases partial[b][0][c][t]
        partial[((size_t)b * NCH * CC + c) * HW + t] = e * __builtin_amdgcn_rcpf(s);
}

// ---------------- K3: pooling (R10 pool5, unchanged) ----------------------
// Grid (16 b, 16 d-tiles of 64, 5 c-groups of 16) = 1280 blocks = 20
// waves/CU. imgT traffic 5x = 64 MB. Thread owns d = d0 + lane (coalesced
// b32); wave owns 4 classes; per h-quad: 4 b32 VMEM + 4 broadcast
// ds_read_b128 (same-address -> conflict-free) + 16 v_fma.
__global__ __launch_bounds__(256) void pool5_k(const float* __restrict__ imgT,
                                               const float* __restrict__ partial,
                                               float* __restrict__ out) {
    __shared__ float ct[PG * HW];                 // 12544 B
    const int b  = blockIdx.x;
    const int d0 = blockIdx.y * 64;
    const int cg = blockIdx.z * PG;
    const int t  = threadIdx.x;
    const int w  = t >> 6, l = t & 63;

    // coef rows live at partial[b][0][c][:] (aliased by softmax_k)
    const float4* cs = (const float4*)(partial + ((size_t)b * NCH * CC + cg) * HW);
    float4* cd = (float4*)ct;
    for (int j = t; j < PG * HW / 4; j += 256) cd[j] = cs[j];
    __syncthreads();

    const float* ib  = imgT + (size_t)b * HW * DD + d0 + l;
    const float* cr0 = ct + (4 * w) * HW;

    float a0 = 0.f, a1 = 0.f, a2 = 0.f, a3 = 0.f;
    for (int h = 0; h < HW; h += 4) {
        float i0 = ib[(size_t)(h    ) * DD];
        float i1 = ib[(size_t)(h + 1) * DD];
        float i2 = ib[(size_t)(h + 2) * DD];
        float i3 = ib[(size_t)(h + 3) * DD];
        float4 c0v = *(const float4*)(cr0 + h);               // broadcast b128
        float4 c1v = *(const float4*)(cr0 + HW + h);
        float4 c2v = *(const float4*)(cr0 + 2 * HW + h);
        float4 c3v = *(const float4*)(cr0 + 3 * HW + h);
        a0 = fmaf(c0v.x, i0, fmaf(c0v.y, i1, fmaf(c0v.z, i2, fmaf(c0v.w, i3, a0))));
        a1 = fmaf(c1v.x, i0, fmaf(c1v.y, i1, fmaf(c1v.z, i2, fmaf(c1v.w, i3, a1))));
        a2 = fmaf(c2v.x, i0, fmaf(c2v.y, i1, fmaf(c2v.z, i2, fmaf(c2v.w, i3, a2))));
        a3 = fmaf(c3v.x, i0, fmaf(c3v.y, i1, fmaf(c3v.z, i2, fmaf(c3v.w, i3, a3))));
    }

    float* ob = out + ((size_t)b * CC + cg + 4 * w) * DD + d0 + l;
    ob[0]              = a0;
    ob[DD]             = a1;
    ob[2 * (size_t)DD] = a2;
    ob[3 * (size_t)DD] = a3;
}

extern "C" void kernel_launch(void* const* d_in, const int* in_sizes, int n_in,
                              void* d_out, int out_size, void* d_ws, size_t ws_size,
                              hipStream_t stream) {
    // inputs: [0]=batch_size(int,1) [1]=img [2]=word [3]=fc_a_w [4]=fc_a_b
    const float* img  = (const float*)d_in[1];
    const float* word = (const float*)d_in[2];
    const float* fa   = (const float*)d_in[3];
    float* out = (float*)d_out;

    // workspace (floats): partial[16][8][80][196] = 8.03 MB | imgT[3136][1024] = 12.85 MB
    float* partial = (float*)d_ws;
    float* imgT    = partial + (size_t)BB * NCH * CC * HW;

    scores_k<<<dim3((NSP + 255) / 256, NCH, NCQ), 256, 0, stream>>>(img, word, fa, partial, imgT);
    softmax_k<<<BB * CC, 256, 0, stream>>>(partial);
    pool5_k<<<dim3(BB, DD / 64, CC / PG), 256, 0, stream>>>(imgT, partial, out);
}

// Round 13
// 154.524 us; speedup vs baseline: 1.0842x; 1.0842x over previous
//
#include <hip/hip_runtime.h>

#define BB 16
#define CC 80
#define DD 1024
#define HW 196
#define NSP (BB * HW)        // 3136 = 49 full waves, zero lane waste
#define NCH 8                // d-chunks of 128
#define DCH 128
#define CPB 4                // classes per scores block
#define NCQ (CC / CPB)       // 20 class-groups -> 2080 blocks (proven residency)
#define PG 16                // classes per pool block (4 per wave)
#define TWO_LOG2E 2.8853900817779268f

typedef float v2f __attribute__((ext_vector_type(2)));

// ---------------- K1: scores + imgT side-product, PACKED-F32 inner ----------
// R5-proven structure (NCH=8, CPB=4, 2080 blocks; NO sched_barrier -- R12
// proved fencing regresses). Inner loop on float2 ext-vectors so the backend
// can select v_pk_mul_f32 / v_pk_add_f32 / v_pk_fma_f32 for the 3 full-rate
// ops (exp2/rcp stay scalar quarter-rate; they are the 16 of 22 cyc floor).
// Stores x = -2*log2e * sum_d fa[d]/(e^{2 img w}+1); affine remainder
// cancels in softmax; exp2(x) == softmax numerator pre-max.
__global__ __launch_bounds__(256) void scores_k(const float* __restrict__ img,
                                                const float* __restrict__ word,
                                                const float* __restrict__ fa,
                                                float* __restrict__ partial,
                                                float* __restrict__ imgT) {
    const int g = blockIdx.x * 256 + threadIdx.x;
    if (g >= NSP) return;                           // wave-uniform exit
    const int b  = g / HW;
    const int hw = g - b * HW;
    const int d0 = blockIdx.y * DCH;
    const int c0 = blockIdx.z * CPB;

    const float* ip = img + ((size_t)b * DD + d0) * HW + hw;

    v2f p[CPB];
#pragma unroll
    for (int k = 0; k < CPB; ++k) p[k] = (v2f)(0.f);

    for (int q = 0; q < DCH / 32; ++q) {            // 4 quarters of 32 d
        float iv[32];
        const float* qp = ip + (size_t)q * 32 * HW;
#pragma unroll
        for (int i = 0; i < 32; ++i)
            iv[i] = qp[(size_t)i * HW];

        if (blockIdx.z == 0) {                       // block-uniform branch
            float4* tp = (float4*)(imgT + (size_t)g * DD + d0 + q * 32);
#pragma unroll
            for (int i = 0; i < 8; ++i)
                tp[i] = make_float4(iv[4 * i], iv[4 * i + 1], iv[4 * i + 2], iv[4 * i + 3]);
        }

        v2f iv2[16];
#pragma unroll
        for (int i = 0; i < 16; ++i)                 // pk-mul pre-scale
            iv2[i] = (v2f){iv[2 * i], iv[2 * i + 1]} * (v2f)(TWO_LOG2E);

        const float* fp = fa + d0 + q * 32;          // uniform -> SGPRs
#pragma unroll
        for (int k = 0; k < CPB; ++k) {
            const float* wp = word + (size_t)(c0 + k) * DD + d0 + q * 32;
            v2f pa = (v2f)(0.f), pb = (v2f)(0.f);
#pragma unroll
            for (int i = 0; i < 16; i += 2) {
                v2f w0 = {wp[2 * i],     wp[2 * i + 1]};
                v2f w1 = {wp[2 * i + 2], wp[2 * i + 3]};
                v2f y0 = iv2[i]     * w0;            // v_pk_mul_f32
                v2f y1 = iv2[i + 1] * w1;
                v2f e0 = {__builtin_amdgcn_exp2f(y0.x), __builtin_amdgcn_exp2f(y0.y)};
                v2f e1 = {__builtin_amdgcn_exp2f(y1.x), __builtin_amdgcn_exp2f(y1.y)};
                v2f d0v = e0 + (v2f)(1.f);           // v_pk_add_f32
                v2f d1v = e1 + (v2f)(1.f);
                v2f r0 = {__builtin_amdgcn_rcpf(d0v.x), __builtin_amdgcn_rcpf(d0v.y)};
                v2f r1 = {__builtin_amdgcn_rcpf(d1v.x), __builtin_amdgcn_rcpf(d1v.y)};
                v2f f0 = {fp[2 * i],     fp[2 * i + 1]};
                v2f f1 = {fp[2 * i + 2], fp[2 * i + 3]};
                pa = __builtin_elementwise_fma(f0, r0, pa);   // v_pk_fma_f32
                pb = __builtin_elementwise_fma(f1, r1, pb);
            }
            p[k] += pa + pb;
        }
    }

#pragma unroll
    for (int k = 0; k < CPB; ++k)
        partial[(((size_t)b * NCH + blockIdx.y) * CC + (c0 + k)) * HW + hw]
            = (-TWO_LOG2E) * (p[k].x + p[k].y);
}

// ---------------- K2: standalone softmax (proven shape, unchanged) ---------
__global__ __launch_bounds__(256) void softmax_k(float* __restrict__ partial) {
    const int bc = blockIdx.x;
    const int b = bc / CC, c = bc - b * CC;
    const int t = threadIdx.x;

    float x = -3.4e38f;
    if (t < HW) {
        float P = 0.f;
#pragma unroll
        for (int ch = 0; ch < NCH; ++ch)
            P += partial[(((size_t)b * NCH + ch) * CC + c) * HW + t];
        x = P;                                       // already -2*log2e scaled
    }

    __shared__ float rmax[4], rsum[4];
    const int wv = t >> 6;

    float m = x;
#pragma unroll
    for (int off = 32; off >= 1; off >>= 1) m = fmaxf(m, __shfl_xor(m, off, 64));
    if ((t & 63) == 0) rmax[wv] = m;
    __syncthreads();
    m = fmaxf(fmaxf(rmax[0], rmax[1]), fmaxf(rmax[2], rmax[3]));

    float e = (t < HW) ? __builtin_amdgcn_exp2f(x - m) : 0.f;
    float s = e;
#pragma unroll
    for (int off = 32; off >= 1; off >>= 1) s += __shfl_xor(s, off, 64);
    if ((t & 63) == 0) rsum[wv] = s;
    __syncthreads();
    s = rsum[0] + rsum[1] + rsum[2] + rsum[3];

    if (t < HW)   // coef[b][c][t] aliases partial[b][0][c][t]
        partial[((size_t)b * NCH * CC + c) * HW + t] = e * __builtin_amdgcn_rcpf(s);
}

// ---------------- K3: pooling, ILP-BATCHED loads ----------------
// Grid (16 b, 16 d-tiles of 64, 5 c-groups of 16) = 1280 blocks = 20
// waves/CU. Change vs R11: the h-loop batches 28 independent imgT loads
// into registers BEFORE the FMA block (196 = 7 x 28), so each wave keeps
// 28 VMEM in flight instead of ~4 -- phase P was latency-bound, not
// issue-bound. Thread owns d = d0 + lane; wave owns 4 classes; coef rows
// from LDS broadcast b128 (conflict-free).
__global__ __launch_bounds__(256) void pool6_k(const float* __restrict__ imgT,
                                               const float* __restrict__ partial,
                                               float* __restrict__ out) {
    __shared__ float ct[PG * HW];                 // 12544 B
    const int b  = blockIdx.x;
    const int d0 = blockIdx.y * 64;
    const int cg = blockIdx.z * PG;
    const int t  = threadIdx.x;
    const int w  = t >> 6, l = t & 63;

    // coef rows live at partial[b][0][c][:] (aliased by softmax_k)
    const float4* cs = (const float4*)(partial + ((size_t)b * NCH * CC + cg) * HW);
    float4* cd = (float4*)ct;
    for (int j = t; j < PG * HW / 4; j += 256) cd[j] = cs[j];
    __syncthreads();

    const float* ib  = imgT + (size_t)b * HW * DD + d0 + l;
    const float* cr0 = ct + (4 * w) * HW;

    float a0 = 0.f, a1 = 0.f, a2 = 0.f, a3 = 0.f;
    for (int hb = 0; hb < HW; hb += 28) {          // 7 batches of 28
        float iv[28];
#pragma unroll
        for (int j = 0; j < 28; ++j)               // 28 loads in flight
            iv[j] = ib[(size_t)(hb + j) * DD];
#pragma unroll
        for (int j = 0; j < 28; j += 4) {
            const int h = hb + j;
            float4 c0v = *(const float4*)(cr0 + h);           // broadcast b128
            float4 c1v = *(const float4*)(cr0 + HW + h);
            float4 c2v = *(const float4*)(cr0 + 2 * HW + h);
            float4 c3v = *(const float4*)(cr0 + 3 * HW + h);
            a0 = fmaf(c0v.x, iv[j], fmaf(c0v.y, iv[j+1], fmaf(c0v.z, iv[j+2], fmaf(c0v.w, iv[j+3], a0))));
            a1 = fmaf(c1v.x, iv[j], fmaf(c1v.y, iv[j+1], fmaf(c1v.z, iv[j+2], fmaf(c1v.w, iv[j+3], a1))));
            a2 = fmaf(c2v.x, iv[j], fmaf(c2v.y, iv[j+1], fmaf(c2v.z, iv[j+2], fmaf(c2v.w, iv[j+3], a2))));
            a3 = fmaf(c3v.x, iv[j], fmaf(c3v.y, iv[j+1], fmaf(c3v.z, iv[j+2], fmaf(c3v.w, iv[j+3], a3))));
        }
    }

    float* ob = out + ((size_t)b * CC + cg + 4 * w) * DD + d0 + l;
    ob[0]              = a0;
    ob[DD]             = a1;
    ob[2 * (size_t)DD] = a2;
    ob[3 * (size_t)DD] = a3;
}

extern "C" void kernel_launch(void* const* d_in, const int* in_sizes, int n_in,
                              void* d_out, int out_size, void* d_ws, size_t ws_size,
                              hipStream_t stream) {
    // inputs: [0]=batch_size(int,1) [1]=img [2]=word [3]=fc_a_w [4]=fc_a_b
    const float* img  = (const float*)d_in[1];
    const float* word = (const float*)d_in[2];
    const float* fa   = (const float*)d_in[3];
    float* out = (float*)d_out;

    // workspace (floats): partial[16][8][80][196] = 8.03 MB | imgT[3136][1024] = 12.85 MB
    float* partial = (float*)d_ws;
    float* imgT    = partial + (size_t)BB * NCH * CC * HW;

    scores_k<<<dim3((NSP + 255) / 256, NCH, NCQ), 256, 0, stream>>>(img, word, fa, partial, imgT);
    softmax_k<<<BB * CC, 256, 0, stream>>>(partial);
    pool6_k<<<dim3(BB, DD / 64, CC / PG), 256, 0, stream>>>(imgT, partial, out);
}